// Round 7
// baseline (120.345 us; speedup 1.0000x reference)
//
#include <hip/hip_runtime.h>
#include <hip/hip_bf16.h>

#define NQ_ 30000
#define NC_ 16
#define C_  128
#define NS_ 8192
#define QB  16
#define NBLK (NQ_/QB)   // 1875

typedef __attribute__((ext_vector_type(4))) float  f32x4;
typedef __attribute__((ext_vector_type(8))) short  s16x8;

// workspace layout (float offsets)
#define NCHK 64
#define WS_PART  0                      // 16 cls * 64 chunks * 128 = 131072
#define WS_PCNT  131072                 // 16*64 = 1024
#define WS_T     132096                 // 2048  (protos @ Wp + b1)
#define WS_PACK  134144                 // shorts: W2frag[16384] Wqfrag[16384] pnfrag[2048]

__device__ inline short f2bf(float x){           // round-to-nearest-even bf16 (cold paths)
  unsigned u = __float_as_uint(x);
  u += 0x7fffu + ((u >> 16) & 1u);
  return (short)(u >> 16);
}

__device__ inline unsigned pk2(float lo, float hi){  // v_cvt_pk_bf16_f32 (RNE)
  __hip_bfloat162 r = __float22bfloat162_rn(float2{lo, hi});
  union { __hip_bfloat162 b; unsigned u; } c; c.b = r;
  return c.u;
}

// ---- kernel A: blocks 0..63 proto partial sums (support read ONCE);
//      blocks 64..95 W2/Wq pack ----
__global__ __launch_bounds__(128) void protoA(const float* __restrict__ sf,
                                              const int* __restrict__ lbl,
                                              const float* __restrict__ W1,
                                              const float* __restrict__ W2,
                                              float* __restrict__ ws){
  const int b = blockIdx.x;
  const int t = threadIdx.x;
  if (b < NCHK){
    const int r0 = b * (NS_/NCHK);      // 128 rows per chunk
    float a[NC_];
    float cn[NC_];
    #pragma unroll
    for (int k = 0; k < NC_; ++k){ a[k] = 0.f; cn[k] = 0.f; }
    for (int r = r0; r < r0 + NS_/NCHK; ++r){
      const float v = sf[(size_t)r*C_ + t];
      const int   l = lbl[r];
      #pragma unroll
      for (int k = 0; k < NC_; ++k){
        const bool m = (l == k);
        a[k]  += m ? v   : 0.f;
        cn[k] += m ? 1.f : 0.f;
      }
    }
    #pragma unroll
    for (int k = 0; k < NC_; ++k){
      ws[WS_PART + ((size_t)k*NCHK + b)*C_ + t] = a[k];
      if (t == 0) ws[WS_PCNT + k*NCHK + b] = cn[k];
    }
  } else {
    // pack W2 (g<16384) / Wq (g>=16384) into MFMA B-fragment order
    short* packo = (short*)(ws + WS_PACK);
    const int g0 = (b - NCHK)*1024 + t*8;
    const int gg = g0 & 16383;
    const int ln = (gg >> 3) & 63, ks = (gg >> 9) & 3, wvv = gg >> 11;
    const int kb = ks*32 + ((ln >> 4) & 3)*8;
    const int col = wvv*16 + (ln & 15);
    const float* src = (g0 < 16384) ? W2 : W1;    // Wq = W1 rows [0,128)
    s16x8 v;
    #pragma unroll
    for (int i = 0; i < 8; ++i) v[i] = f2bf(src[(size_t)(kb + i)*C_ + col]);
    *(s16x8*)&packo[g0] = v;
  }
}

// ---- kernel B: per-class finalize + pn-pack + tmat (16 blocks x 128 thr) ----
__global__ __launch_bounds__(128) void protoB(const float* __restrict__ W1,
                                              const float* __restrict__ b1,
                                              float* __restrict__ ws){
  __shared__ float pr[C_];
  __shared__ float rns;
  const int n = blockIdx.x;
  const int h = threadIdx.x;
  float s = 0.f;
  #pragma unroll 8
  for (int ch = 0; ch < NCHK; ++ch) s += ws[WS_PART + ((size_t)n*NCHK + ch)*C_ + h];
  float cnt = 0.f;
  #pragma unroll 8
  for (int ch = 0; ch < NCHK; ++ch) cnt += ws[WS_PCNT + n*NCHK + ch];
  const float pv = (cnt > 0.f) ? s / fmaxf(cnt, 1.f) : 0.f;
  pr[h] = pv;
  __syncthreads();
  if (h < 64){
    float q = pr[h]*pr[h] + pr[h+64]*pr[h+64];
    q += __shfl_xor(q, 1);  q += __shfl_xor(q, 2);  q += __shfl_xor(q, 4);
    q += __shfl_xor(q, 8);  q += __shfl_xor(q, 16); q += __shfl_xor(q, 32);
    if (h == 0) rns = 1.f / fmaxf(sqrtf(q), 1e-8f);
  }
  __syncthreads();
  // pn-pack: thread h handles k=h for class n
  {
    short* packo = (short*)(ws + WS_PACK);
    const int k = h;
    const int gg = ((k >> 5)*64 + ((k >> 3) & 3)*16 + n)*8 + (k & 7);
    packo[32768 + gg] = f2bf(pv * rns);
  }
  // tmat: ws[WS_T + n*C_ + h] = b1[h] + sum_c pr[c]*W1[(C+c)*C+h]
  float acc = b1[h];
  #pragma unroll 8
  for (int c = 0; c < C_; ++c) acc = fmaf(pr[c], W1[(size_t)(C_ + c)*C_ + h], acc);
  ws[WS_T + n*C_ + h] = acc;
}

// ---- fused main: R6 structure; only bf16 conversion instrs changed ----
__global__ __launch_bounds__(512) void fused_main(const float* __restrict__ qfeat,
                                                  const float* __restrict__ W1,
                                                  const float* __restrict__ b2,
                                                  const float* __restrict__ ws,
                                                  float* __restrict__ out){
  __shared__ __align__(16) char un[16384];   // qfs[16][132] f32, then hfrag[4*2048] bf16
  __shared__ float qw[QB][132];
  __shared__ float tl16[NC_][132];
  __shared__ float cosl[QB][NC_];
  __shared__ float rqn[QB];
  __shared__ float wcl[C_];

  float (*qfs)[132] = (float(*)[132])un;
  short* hfrag = (short*)un;

  const int t    = threadIdx.x;
  const int lane = t & 63;
  const int wv   = t >> 6;
  const int qbase = blockIdx.x * QB;
  float* out_cos = out + (size_t)NQ_ * NC_ * C_;
  const short* pack = (const short*)(ws + WS_PACK);

  // stage qf (16x128), t-matrix, Wc — all coalesced
  {
    int idx = t * 4; int q = idx >> 7; int c = idx & 127;
    *(f32x4*)&qfs[q][c]  = *(const f32x4*)(qfeat + (size_t)qbase*C_ + idx);
    *(f32x4*)&tl16[q][c] = *(const f32x4*)(ws + WS_T + idx);
    if (t < 32) *(f32x4*)&wcl[t*4] = *(const f32x4*)(W1 + 2*C_*C_ + t*4);
  }
  __syncthreads();

  // 1/max(||q||, eps)
  if (t < 128){
    int q = t >> 3; int c0 = (t & 7) * 16;
    float s = 0.f;
    #pragma unroll
    for (int m = 0; m < 16; ++m){ float v = qfs[q][c0+m]; s = fmaf(v, v, s); }
    s += __shfl_xor(s, 1); s += __shfl_xor(s, 2); s += __shfl_xor(s, 4);
    if ((t & 7) == 0) rqn[q] = 1.f / fmaxf(sqrtf(s), 1e-8f);
  }

  const int fr = lane & 15;
  const int fg = lane >> 4;
  const int ocol = wv*16 + fr;

  // A-fragments of qf; B-fragments of W2/Wq coalesced from pack
  s16x8 qfr[4], w2f[4], wqf[4];
  #pragma unroll
  for (int ks = 0; ks < 4; ++ks){
    const int c0 = ks*32 + fg*8;
    f32x4 a = *(const f32x4*)&qfs[fr][c0];
    f32x4 b = *(const f32x4*)&qfs[fr][c0+4];
    union { unsigned u[4]; s16x8 v; } cv;
    cv.u[0] = pk2(a[0], a[1]);
    cv.u[1] = pk2(a[2], a[3]);
    cv.u[2] = pk2(b[0], b[1]);
    cv.u[3] = pk2(b[2], b[3]);
    qfr[ks] = cv.v;
    w2f[ks] = *(const s16x8*)&pack[((wv*4 + ks)*64 + lane)*8];
    wqf[ks] = *(const s16x8*)&pack[16384 + ((wv*4 + ks)*64 + lane)*8];
  }
  const float b2v = b2[ocol];
  __syncthreads();   // rqn ready; all qfs reads done

  // qW = qf @ Wq
  {
    f32x4 dq = {0.f,0.f,0.f,0.f};
    #pragma unroll
    for (int ks = 0; ks < 4; ++ks)
      dq = __builtin_amdgcn_mfma_f32_16x16x32_bf16(qfr[ks], wqf[ks], dq, 0,0,0);
    #pragma unroll
    for (int r = 0; r < 4; ++r) qw[fg*4 + r][ocol] = dq[r];
  }
  // cos = (qf @ pn^T) * rqn   (wave 0)
  if (wv == 0){
    s16x8 pnf[4];
    #pragma unroll
    for (int ks = 0; ks < 4; ++ks)
      pnf[ks] = *(const s16x8*)&pack[32768 + (ks*64 + lane)*8];
    f32x4 dc = {0.f,0.f,0.f,0.f};
    #pragma unroll
    for (int ks = 0; ks < 4; ++ks)
      dc = __builtin_amdgcn_mfma_f32_16x16x32_bf16(qfr[ks], pnf[ks], dc, 0,0,0);
    #pragma unroll
    for (int r = 0; r < 4; ++r){
      const int q = fg*4 + r;
      const float cv = dc[r] * rqn[q];
      cosl[q][fr] = cv;
      out_cos[(size_t)(qbase + q)*NC_ + fr] = cv;
    }
  }
  __syncthreads();   // qw, cosl ready; qfs dead -> hfrag live

  // phase-A constants: wave wv handles (ksA, ii0); lane -> (class na, k-group ga)
  const int na  = lane & 15;
  const int ga  = lane >> 4;
  const int ksA = wv >> 1;
  const int ii0 = (wv & 1) * 4;
  const int k0  = ksA*32 + ga*8 + ii0;
  const f32x4 t4  = *(const f32x4*)&tl16[na][k0];
  const f32x4 wc4 = *(const f32x4*)&wcl[k0];

  #pragma unroll
  for (int chunk = 0; chunk < 4; ++chunk){
    const int q0 = chunk * 4;
    // phase A: H = relu(qW + t_n + cos*Wc) -> bf16 fragments in LDS
    #pragma unroll
    for (int qq = 0; qq < 4; ++qq){
      const int q = q0 + qq;
      f32x4 qw4 = *(const f32x4*)&qw[q][k0];
      const float cv = cosl[q][na];
      float h0 = fmaxf(fmaf(cv, wc4[0], qw4[0] + t4[0]), 0.f);
      float h1 = fmaxf(fmaf(cv, wc4[1], qw4[1] + t4[1]), 0.f);
      float h2 = fmaxf(fmaf(cv, wc4[2], qw4[2] + t4[2]), 0.f);
      float h3 = fmaxf(fmaf(cv, wc4[3], qw4[3] + t4[3]), 0.f);
      union { unsigned u[2]; uint2 d; } hv;
      hv.u[0] = pk2(h0, h1);
      hv.u[1] = pk2(h2, h3);
      *(uint2*)&hfrag[qq*2048 + ksA*512 + lane*8 + ii0] = hv.d;
    }
    __syncthreads();
    // phase B: sim = H @ W2 + b2
    #pragma unroll
    for (int qq = 0; qq < 4; ++qq){
      s16x8 a0 = *(const s16x8*)&hfrag[qq*2048 +    0 + lane*8];
      s16x8 a1 = *(const s16x8*)&hfrag[qq*2048 +  512 + lane*8];
      s16x8 a2 = *(const s16x8*)&hfrag[qq*2048 + 1024 + lane*8];
      s16x8 a3 = *(const s16x8*)&hfrag[qq*2048 + 1536 + lane*8];
      f32x4 acc = {b2v, b2v, b2v, b2v};
      acc = __builtin_amdgcn_mfma_f32_16x16x32_bf16(a0, w2f[0], acc, 0,0,0);
      acc = __builtin_amdgcn_mfma_f32_16x16x32_bf16(a1, w2f[1], acc, 0,0,0);
      acc = __builtin_amdgcn_mfma_f32_16x16x32_bf16(a2, w2f[2], acc, 0,0,0);
      acc = __builtin_amdgcn_mfma_f32_16x16x32_bf16(a3, w2f[3], acc, 0,0,0);
      const size_t qout = (size_t)(qbase + q0 + qq) * (NC_*C_);
      #pragma unroll
      for (int r = 0; r < 4; ++r)
        out[qout + (fg*4 + r)*C_ + ocol] = acc[r];
    }
    __syncthreads();
  }
}

extern "C" void kernel_launch(void* const* d_in, const int* in_sizes, int n_in,
                              void* d_out, int out_size, void* d_ws, size_t ws_size,
                              hipStream_t stream){
  const float* sf  = (const float*)d_in[0];
  const int*   lbl = (const int*)  d_in[1];
  const float* qf  = (const float*)d_in[2];
  const float* W1  = (const float*)d_in[3];
  const float* b1  = (const float*)d_in[4];
  const float* W2  = (const float*)d_in[5];
  const float* b2  = (const float*)d_in[6];
  float* ws  = (float*)d_ws;
  float* out = (float*)d_out;

  protoA<<<NCHK + 32, 128, 0, stream>>>(sf, lbl, W1, W2, ws);
  protoB<<<NC_, 128, 0, stream>>>(W1, b1, ws);
  fused_main<<<NBLK, 512, 0, stream>>>(qf, W1, b2, ws, out);
}

// Round 9
// 88.392 us; speedup vs baseline: 1.3615x; 1.3615x over previous
//
#include <hip/hip_runtime.h>

#define NQ_ 30000
#define NC_ 16
#define C_  128
#define NS_ 8192
#define QB  16
#define NBLK (NQ_/QB)   // 1875

typedef __attribute__((ext_vector_type(4))) float  f32x4;
typedef __attribute__((ext_vector_type(8))) short  s16x8;

// workspace layout (float offsets)
#define WS_PART  0         // 16 cls * 16 chunks * 128 = 32768
#define WS_PCNT  32768     // 256
#define WS_T     33024     // 2048  (protos @ Wp + b1)
#define WS_PACK  35072     // shorts: W2frag[16384] Wqfrag[16384] pnfrag[2048]

__device__ inline short f2bf(float x){           // round-to-nearest-even bf16
  unsigned u = __float_as_uint(x);
  u += 0x7fffu + ((u >> 16) & 1u);
  return (short)(u >> 16);
}

// ---- kernel A: proto partial sums (blocks 0..255) + W2/Wq pack (blocks 256..287) ----
__global__ __launch_bounds__(128) void protoA(const float* __restrict__ sf,
                                              const int* __restrict__ lbl,
                                              const float* __restrict__ W1,
                                              const float* __restrict__ W2,
                                              float* __restrict__ ws){
  const int b = blockIdx.x;
  const int t = threadIdx.x;
  if (b < 256){
    const int cls = b >> 4;
    const int ch  = b & 15;
    const int r0  = ch * (NS_/16);
    float s = 0.f; int cnt = 0;
    #pragma unroll 4
    for (int r = r0; r < r0 + NS_/16; ++r){
      if (lbl[r] == cls){ s += sf[(size_t)r*C_ + t]; ++cnt; }
    }
    ws[WS_PART + (cls*16 + ch)*C_ + t] = s;
    if (t == 0) ws[WS_PCNT + cls*16 + ch] = (float)cnt;
  } else {
    // pack W2 (g<16384) / Wq (g>=16384) into MFMA B-fragment order
    short* packo = (short*)(ws + WS_PACK);
    const int g0 = (b - 256)*1024 + t*8;
    const int gg = g0 & 16383;
    const int ln = (gg >> 3) & 63, ks = (gg >> 9) & 3, wvv = gg >> 11;
    const int kb = ks*32 + ((ln >> 4) & 3)*8;
    const int col = wvv*16 + (ln & 15);
    const float* src = (g0 < 16384) ? W2 : W1;    // Wq = W1 rows [0,128)
    s16x8 v;
    #pragma unroll
    for (int i = 0; i < 8; ++i) v[i] = f2bf(src[(size_t)(kb + i)*C_ + col]);
    *(s16x8*)&packo[g0] = v;
  }
}

// ---- kernel B: per-class finalize + pn + tmat + pn-pack (16 blocks x 128 thr) ----
__global__ __launch_bounds__(128) void protoB(const float* __restrict__ W1,
                                              const float* __restrict__ b1,
                                              float* __restrict__ ws){
  __shared__ float pr[C_];
  __shared__ float rns;
  const int n = blockIdx.x;
  const int h = threadIdx.x;
  float s = 0.f;
  #pragma unroll
  for (int ch = 0; ch < 16; ++ch) s += ws[WS_PART + (n*16 + ch)*C_ + h];
  float cnt = 0.f;
  #pragma unroll
  for (int ch = 0; ch < 16; ++ch) cnt += ws[WS_PCNT + n*16 + ch];
  const float pv = (cnt > 0.f) ? s / fmaxf(cnt, 1.f) : 0.f;
  pr[h] = pv;
  __syncthreads();
  if (h < 64){
    float q = pr[h]*pr[h] + pr[h+64]*pr[h+64];
    q += __shfl_xor(q, 1);  q += __shfl_xor(q, 2);  q += __shfl_xor(q, 4);
    q += __shfl_xor(q, 8);  q += __shfl_xor(q, 16); q += __shfl_xor(q, 32);
    if (h == 0) rns = 1.f / fmaxf(sqrtf(q), 1e-8f);
  }
  __syncthreads();
  // pn-pack: thread h handles k=h for class n
  {
    short* packo = (short*)(ws + WS_PACK);
    const int k = h;
    const int gg = ((k >> 5)*64 + ((k >> 3) & 3)*16 + n)*8 + (k & 7);
    packo[32768 + gg] = f2bf(pv * rns);
  }
  // tmat: ws[WS_T + n*C_ + h] = b1[h] + sum_c pr[c]*W1[(C+c)*C+h]
  float acc = b1[h];
  #pragma unroll 8
  for (int c = 0; c < C_; ++c) acc = fmaf(pr[c], W1[(size_t)(C_ + c)*C_ + h], acc);
  ws[WS_T + n*C_ + h] = acc;
}

// ---- fused main: 256 thr, 4 waves, QB=16; each wave owns 2 col-tiles ----
__global__ __launch_bounds__(256, 4) void fused_main(const float* __restrict__ qfeat,
                                                     const float* __restrict__ W1,
                                                     const float* __restrict__ b2,
                                                     const float* __restrict__ ws,
                                                     float* __restrict__ out){
  __shared__ __align__(16) char un[16384];   // qfs[16][132] f32, then hfrag[4q*2048] bf16
  __shared__ float qw[QB][132];
  __shared__ float tl16[NC_][132];
  __shared__ float cosl[QB][NC_];
  __shared__ float rqn[QB];
  __shared__ float wcl[C_];

  float (*qfs)[132] = (float(*)[132])un;
  short* hfrag = (short*)un;

  const int t    = threadIdx.x;
  const int lane = t & 63;
  const int wv   = t >> 6;          // 0..3
  const int fr   = lane & 15;
  const int fg   = lane >> 4;
  const int qbase = blockIdx.x * QB;
  float* out_cos = out + (size_t)NQ_ * NC_ * C_;
  const short* pack = (const short*)(ws + WS_PACK);

  // stage qf (16x128), t-matrix, Wc — all coalesced (8 dwords/thread each)
  {
    const int idx = t * 8, q = idx >> 7, c = idx & 127;
    *(f32x4*)&qfs[q][c]      = *(const f32x4*)(qfeat + (size_t)qbase*C_ + idx);
    *(f32x4*)&qfs[q][c+4]    = *(const f32x4*)(qfeat + (size_t)qbase*C_ + idx + 4);
    *(f32x4*)&tl16[q][c]     = *(const f32x4*)(ws + WS_T + idx);
    *(f32x4*)&tl16[q][c+4]   = *(const f32x4*)(ws + WS_T + idx + 4);
    if (t < 32) *(f32x4*)&wcl[t*4] = *(const f32x4*)(W1 + 2*C_*C_ + t*4);
  }
  __syncthreads();

  // 1/max(||q||, eps)
  if (t < 128){
    int q = t >> 3; int c0 = (t & 7) * 16;
    float s = 0.f;
    #pragma unroll
    for (int m = 0; m < 16; ++m){ float v = qfs[q][c0+m]; s = fmaf(v, v, s); }
    s += __shfl_xor(s, 1); s += __shfl_xor(s, 2); s += __shfl_xor(s, 4);
    if ((t & 7) == 0) rqn[q] = 1.f / fmaxf(sqrtf(s), 1e-8f);
  }

  // A-fragments of qf (row = query fr)
  s16x8 qfr[4];
  #pragma unroll
  for (int ks = 0; ks < 4; ++ks){
    const int c0 = ks*32 + fg*8;
    f32x4 a = *(const f32x4*)&qfs[fr][c0];
    f32x4 b = *(const f32x4*)&qfs[fr][c0+4];
    s16x8 v;
    v[0]=f2bf(a[0]); v[1]=f2bf(a[1]); v[2]=f2bf(a[2]); v[3]=f2bf(a[3]);
    v[4]=f2bf(b[0]); v[5]=f2bf(b[1]); v[6]=f2bf(b[2]); v[7]=f2bf(b[3]);
    qfr[ks] = v;
  }
  // B-fragments of W2 for this wave's two col-tiles
  s16x8 w2f[2][4];
  float b2v[2];
  #pragma unroll
  for (int j = 0; j < 2; ++j){
    const int tt = wv*2 + j;
    #pragma unroll
    for (int ks = 0; ks < 4; ++ks)
      w2f[j][ks] = *(const s16x8*)&pack[((tt*4 + ks)*64 + lane)*8];
    b2v[j] = b2[tt*16 + fr];
  }
  __syncthreads();   // rqn ready; all qfs reads done

  // qW = qf @ Wq : wave wv covers col-tiles wv*2, wv*2+1
  #pragma unroll
  for (int j = 0; j < 2; ++j){
    const int tt = wv*2 + j;
    f32x4 dq = {0.f,0.f,0.f,0.f};
    #pragma unroll
    for (int ks = 0; ks < 4; ++ks)
      dq = __builtin_amdgcn_mfma_f32_16x16x32_bf16(qfr[ks],
             *(const s16x8*)&pack[16384 + ((tt*4 + ks)*64 + lane)*8], dq, 0,0,0);
    #pragma unroll
    for (int r = 0; r < 4; ++r) qw[fg*4 + r][tt*16 + fr] = dq[r];
  }
  // cos = (qf @ pn^T) * rqn   (wave 0)
  if (wv == 0){
    f32x4 dc = {0.f,0.f,0.f,0.f};
    #pragma unroll
    for (int ks = 0; ks < 4; ++ks)
      dc = __builtin_amdgcn_mfma_f32_16x16x32_bf16(qfr[ks],
             *(const s16x8*)&pack[32768 + (ks*64 + lane)*8], dc, 0,0,0);
    #pragma unroll
    for (int r = 0; r < 4; ++r){
      const int q = fg*4 + r;
      const float cv = dc[r] * rqn[q];
      cosl[q][fr] = cv;
      out_cos[(size_t)(qbase + q)*NC_ + fr] = cv;
    }
  }
  __syncthreads();   // qw, cosl ready; qfs dead -> hfrag live

  // phase-A constants: wave wv == k-step ksA; lane -> (class fr, k-group fg)
  const int k0 = wv*32 + fg*8;
  const f32x4 t8a = *(const f32x4*)&tl16[fr][k0];
  const f32x4 t8b = *(const f32x4*)&tl16[fr][k0+4];
  const f32x4 w8a = *(const f32x4*)&wcl[k0];
  const f32x4 w8b = *(const f32x4*)&wcl[k0+4];

  #pragma unroll
  for (int chunk = 0; chunk < 4; ++chunk){
    const int q0 = chunk * 4;
    // phase A: H = relu(qW + t_n + cos*Wc) -> bf16 fragments (full s16x8/thread/query)
    #pragma unroll
    for (int qq = 0; qq < 4; ++qq){
      const int q = q0 + qq;
      f32x4 qa = *(const f32x4*)&qw[q][k0];     // broadcast within fg-group
      f32x4 qb = *(const f32x4*)&qw[q][k0+4];
      const float cv = cosl[q][fr];
      s16x8 hv;
      #pragma unroll
      for (int jj = 0; jj < 4; ++jj)
        hv[jj] = f2bf(fmaxf(fmaf(cv, w8a[jj], qa[jj] + t8a[jj]), 0.f));
      #pragma unroll
      for (int jj = 0; jj < 4; ++jj)
        hv[4+jj] = f2bf(fmaxf(fmaf(cv, w8b[jj], qb[jj] + t8b[jj]), 0.f));
      *(s16x8*)&hfrag[qq*2048 + wv*512 + lane*8] = hv;   // b128, conflict-free
    }
    __syncthreads();
    // phase B: sim = H @ W2 + b2 ; one ds_read set feeds both col-tiles
    #pragma unroll
    for (int qq = 0; qq < 4; ++qq){
      const short* hb = &hfrag[qq*2048 + lane*8];
      s16x8 a0 = *(const s16x8*)&hb[0];
      s16x8 a1 = *(const s16x8*)&hb[512];
      s16x8 a2 = *(const s16x8*)&hb[1024];
      s16x8 a3 = *(const s16x8*)&hb[1536];
      const size_t qout = (size_t)(qbase + q0 + qq) * (NC_*C_);
      #pragma unroll
      for (int j = 0; j < 2; ++j){
        f32x4 acc = {b2v[j], b2v[j], b2v[j], b2v[j]};
        acc = __builtin_amdgcn_mfma_f32_16x16x32_bf16(a0, w2f[j][0], acc, 0,0,0);
        acc = __builtin_amdgcn_mfma_f32_16x16x32_bf16(a1, w2f[j][1], acc, 0,0,0);
        acc = __builtin_amdgcn_mfma_f32_16x16x32_bf16(a2, w2f[j][2], acc, 0,0,0);
        acc = __builtin_amdgcn_mfma_f32_16x16x32_bf16(a3, w2f[j][3], acc, 0,0,0);
        const int ocol = (wv*2 + j)*16 + fr;
        #pragma unroll
        for (int r = 0; r < 4; ++r)
          out[qout + (fg*4 + r)*C_ + ocol] = acc[r];
      }
    }
    __syncthreads();
  }
}

extern "C" void kernel_launch(void* const* d_in, const int* in_sizes, int n_in,
                              void* d_out, int out_size, void* d_ws, size_t ws_size,
                              hipStream_t stream){
  const float* sf  = (const float*)d_in[0];
  const int*   lbl = (const int*)  d_in[1];
  const float* qf  = (const float*)d_in[2];
  const float* W1  = (const float*)d_in[3];
  const float* b1  = (const float*)d_in[4];
  const float* W2  = (const float*)d_in[5];
  const float* b2  = (const float*)d_in[6];
  float* ws  = (float*)d_ws;
  float* out = (float*)d_out;

  protoA<<<288, 128, 0, stream>>>(sf, lbl, W1, W2, ws);
  protoB<<<NC_, 128, 0, stream>>>(W1, b1, ws);
  fused_main<<<NBLK, 256, 0, stream>>>(qf, W1, b2, ws, out);
}